// Round 9
// baseline (342.515 us; speedup 1.0000x reference)
//
#include <hip/hip_runtime.h>

// ---------------- types / helpers ----------------
typedef short bf8s __attribute__((ext_vector_type(8)));   // 8 bf16 (4 VGPRs)
typedef float f32x4 __attribute__((ext_vector_type(4)));

#define MFMA16(a, b, c) __builtin_amdgcn_mfma_f32_16x16x32_bf16(a, b, c, 0, 0, 0)

constexpr int S_ = 512, HID_ = 128, B_ = 128, M_ = B_ * S_;

__device__ inline short f2bf(float f) {  // fp32 -> bf16 (RNE)
  unsigned u = __float_as_uint(f);
  u = (u + 0x7fffu + ((u >> 16) & 1u)) >> 16;
  return (short)u;
}
__device__ inline float bf2f(short s) {
  return __uint_as_float(((unsigned)(unsigned short)s) << 16);
}

// async global->LDS, 16B/lane. LDS dst must be the WAVE-UNIFORM base (hardware
// appends lane*16); global src is per-lane. Tracked by vmcnt; the compiler's
// vmcnt(0) drain before s_barrier guarantees completion.
__device__ __forceinline__ void async16(void* lds, const void* g) {
  __builtin_amdgcn_global_load_lds(
      (const __attribute__((address_space(1))) unsigned int*)g,
      (__attribute__((address_space(3))) unsigned int*)lds, 16, 0, 0);
}

__device__ __forceinline__ bf8s ldsb(const short* base, int byteoff) {
  return *(const bf8s*)((const char*)base + byteoff);
}

__device__ inline float block_red1024(float v, float* red) {
  #pragma unroll
  for (int m = 32; m >= 1; m >>= 1) v += __shfl_xor(v, m);
  __syncthreads();
  if ((threadIdx.x & 63) == 0) red[threadIdx.x >> 6] = v;
  __syncthreads();
  float t = 0.f;
  #pragma unroll
  for (int i = 0; i < 16; ++i) t += red[i];
  return t;
}

// ---------------- FRAGMENT-MAJOR weight layout ----------------
// element (r,c) of an R x C matrix lives at
//   fi = (r>>4)*(16*C) + (c>>5)*512 + ((c>>3)&3)*128 + (r&15)*8 + (c&7)
// 16x32 fragment block (tile=r>>4, ki=c>>5) = 1KB; lane l's bf8s at l*16 bytes:
// ds_read_b128 wave-linear (0 conflicts), DMA source linear.
__device__ inline void mat_info(int mat, const float* qw, const float* kw,
                                const float* vw, const float* aow, const float* iw,
                                const float* fw, const float* cw,
                                const float** src, int* n, int* doff, int* lc) {
  if (mat < 6) {
    int l = mat / 3, which = mat % 3;
    const float* t[3] = {qw, kw, vw};
    *src = t[which] + l * 16384; *n = 16384; *doff = l * 49152 + which * 16384;
    *lc = 7;
  } else if (mat < 8) {
    int l = mat - 6;
    *src = aow + l * 16384; *n = 16384; *doff = 98304 + l * 16384; *lc = 7;
  } else if (mat < 10) {
    *src = iw + (mat - 8) * 65536; *n = 65536; *doff = 131072 + (mat - 8) * 65536;
    *lc = 7;   // Wi: 512 rows x 128 cols
  } else if (mat < 12) {
    *src = fw + (mat - 10) * 65536; *n = 65536; *doff = 262144 + (mat - 10) * 65536;
    *lc = 9;   // Wf: 128 rows x 512 cols
  } else {
    *src = cw; *n = 256; *doff = 393216; *lc = 0;
  }
}

// ---------------- fused quant (blocks 0..12) + embed (blocks 13..) ----------------
// Round-22 version (8-deep load batching, exact order) -- unchanged.
__global__ __launch_bounds__(1024) void k_qe(const float* qw, const float* kw,
    const float* vw, const float* aow, const float* iw, const float* fw,
    const float* cw, short* WQ,
    const int* __restrict__ ids, const float* __restrict__ tok,
    const float* __restrict__ pos, const float* __restrict__ g,
    const float* __restrict__ bb, short* xb) {
  __shared__ float red[16];
  int tid = threadIdx.x;
  if (blockIdx.x < 13) {  // ---- ternary quantization ----
    const float* src; int n, doff, lc;
    mat_info(blockIdx.x, qw, kw, vw, aow, iw, fw, cw, &src, &n, &doff, &lc);
    float s = 0.f;
    if (n >= 8192) {  // n is a multiple of 8192 for all big mats
      for (int i0 = tid; i0 < n; i0 += 8192) {
        float v[8];
        #pragma unroll
        for (int j = 0; j < 8; ++j) v[j] = src[i0 + j * 1024];  // 8 in flight
        #pragma unroll
        for (int j = 0; j < 8; ++j) s += fabsf(v[j]);           // exact order
      }
    } else {
      for (int i = tid; i < n; i += 1024) s += fabsf(src[i]);
    }
    s = block_red1024(s, red);
    float delta = 0.7f * s / (float)n;
    float s2 = 0.f, c2 = 0.f;
    if (n >= 8192) {
      for (int i0 = tid; i0 < n; i0 += 8192) {
        float v[8];
        #pragma unroll
        for (int j = 0; j < 8; ++j) v[j] = src[i0 + j * 1024];
        #pragma unroll
        for (int j = 0; j < 8; ++j) {
          float a = fabsf(v[j]);
          s2 += (a > delta) ? a : 0.f;   // +0.0f: exact identity
          c2 += (a > delta) ? 1.f : 0.f;
        }
      }
    } else {
      for (int i = tid; i < n; i += 1024) {
        float a = fabsf(src[i]);
        if (a > delta) { s2 += a; c2 += 1.f; }
      }
    }
    s2 = block_red1024(s2, red);
    c2 = block_red1024(c2, red);
    float alpha = s2 / fmaxf(c2, 1.f);
    if (lc) {  // output-major fragment write: vector reads + 16B stores
      int nf8 = n >> 3;
      for (int fo8 = tid; fo8 < nf8; fo8 += 1024) {
        int fo = fo8 << 3;
        int tile = fo >> (lc + 4);
        int rem = fo & ((16 << lc) - 1);
        int kblk = rem >> 9;
        int rem2 = rem & 511;
        int sub = rem2 >> 7;
        int r16 = (rem2 >> 3) & 15;
        int r = (tile << 4) | r16;
        int cbase = (kblk << 5) | (sub << 3);
        const float* sp = src + ((size_t)r << lc) + cbase;
        float4 w0 = *(const float4*)(sp);
        float4 w1 = *(const float4*)(sp + 4);
        float wv[8] = {w0.x, w0.y, w0.z, w0.w, w1.x, w1.y, w1.z, w1.w};
        bf8s q;
        #pragma unroll
        for (int j = 0; j < 8; ++j) {
          float w = wv[j];
          q[j] = (fabsf(w) > delta) ? f2bf(w > 0.f ? alpha : -alpha) : (short)0;
        }
        *(bf8s*)(WQ + doff + fo) = q;
      }
    } else {  // clf: row-major scalar
      for (int i = tid; i < n; i += 1024) {
        float w = src[i];
        WQ[doff + i] = (fabsf(w) > delta) ? f2bf(w > 0.f ? alpha : -alpha) : (short)0;
      }
    }
  } else {  // ---- embedding + LN: 2 tokens/wave, float4/lane ----
    int wave = tid >> 6, lane = tid & 63;
    int half = lane >> 5, l32 = lane & 31;
    int t = (blockIdx.x - 13) * 32 + wave * 2 + half;
    int s = t & (S_ - 1);
    int id = ids[t];
    int d0 = l32 * 4;
    float4 te = *(const float4*)(tok + (size_t)id * HID_ + d0);
    float4 pe = *(const float4*)(pos + (size_t)s * HID_ + d0);
    float e0 = te.x + pe.x, e1 = te.y + pe.y, e2 = te.z + pe.z, e3 = te.w + pe.w;
    float sum = e0 + e1 + e2 + e3;
    float ssq = e0 * e0 + e1 * e1 + e2 * e2 + e3 * e3;
    #pragma unroll
    for (int m = 16; m >= 1; m >>= 1) {  // stays within 32-lane half
      sum += __shfl_xor(sum, m);
      ssq += __shfl_xor(ssq, m);
    }
    float mean = sum / 128.f;
    float var = ssq / 128.f - mean * mean;
    float rs = rsqrtf(var + 1e-5f);
    float4 g4 = *(const float4*)(g + d0);
    float4 b4 = *(const float4*)(bb + d0);
    short4 o;
    o.x = f2bf((e0 - mean) * rs * g4.x + b4.x);
    o.y = f2bf((e1 - mean) * rs * g4.y + b4.y);
    o.z = f2bf((e2 - mean) * rs * g4.z + b4.z);
    o.w = f2bf((e3 - mean) * rs * g4.w + b4.w);
    *(short4*)(xb + (size_t)t * HID_ + d0) = o;
  }
}

// ---------------- QKV linear (layer 0): DMA tile + WIDE-store epilogue ---------
__global__ __launch_bounds__(256) void k_qkv(
    const short* __restrict__ A, const short* __restrict__ W,
    const float* __restrict__ b0, const float* __restrict__ b1,
    const float* __restrict__ b2, short* outb) {
  __shared__ short Wl[16384];  // 32KB fragment tile, linear
  int tid = threadIdx.x, lane = tid & 63, wave = tid >> 6;
  int row16 = lane & 15, quad = lane >> 4;
  int tok0 = blockIdx.x * 64 + wave * 16;

  const char* Wm = (const char*)W + blockIdx.y * 32768;
  #pragma unroll
  for (int t = 0; t < 8; ++t)
    async16((char*)Wl + t * 4096 + wave * 1024,
            Wm + t * 4096 + wave * 1024 + lane * 16);

  const short* arow = A + (size_t)(tok0 + row16) * 128 + quad * 8;
  bf8s av[4];
  #pragma unroll
  for (int ki = 0; ki < 4; ++ki) av[ki] = *(const bf8s*)(arow + ki * 32);
  __syncthreads();  // drains DMA

  f32x4 acc[8] = {};
  #pragma unroll
  for (int ki = 0; ki < 4; ++ki)
    #pragma unroll
    for (int ot = 0; ot < 8; ++ot) {
      bf8s b = ldsb(Wl, ot * 4096 + ki * 1024 + lane * 16);  // conflict-free
      acc[ot] = MFMA16(av[ki], b, acc[ot]);
    }
  __syncthreads();  // all weight reads done -> Wl reusable as scratch

  const float* bp = (blockIdx.y == 0) ? b0 : ((blockIdx.y == 1) ? b1 : b2);
  float osc = (blockIdx.y == 0) ? 0.125f : 1.0f;  // fold 1/sqrt(64) into Q
  short* scr = Wl + wave * 2112;  // 16 x 132 per-wave scratch (132: quad-spread)
  #pragma unroll
  for (int ot = 0; ot < 8; ++ot) {
    int col = ot * 16 + row16;
    float bi = bp[col];
    #pragma unroll
    for (int r = 0; r < 4; ++r)
      scr[(quad * 4 + r) * 132 + col] = f2bf((acc[ot][r] + bi) * osc);
  }
  {
    int rr = lane >> 2, cg = lane & 3;
    const short* src = scr + rr * 132 + cg * 32;
    short* dst = outb + (size_t)(tok0 + rr) * 384 + blockIdx.y * 128 + cg * 32;
    #pragma unroll
    for (int j = 0; j < 4; ++j)
      *(bf8s*)(dst + j * 8) = *(const bf8s*)(src + j * 8);
  }
}

// ---------------- fused AO+LN1+FF1+FF2+LN2 [+ next-layer QKV] ----------------
// Round-23: bank-conflict fix for the NON-weight LDS. The 2.69M residual
// conflicts were myX stride 144 (72 words ≡ 8 mod 32: per-quad row offset
// 288 ≡ 0 -> all 4 quads same bank, 4-way on every epilogue scalar) and the
// stash stride 40 (quad offset 16 mod 32: pairwise). Rule: row-stride in words
// ≡ 2 (mod 8) -> quad offsets {0,8,16,24}. myX 144->132, stash 40->36.
// Weight bufs unchanged (fragment-major, conflict-free).
template <int DOQKV>
__global__ __launch_bounds__(512, 4) void k_aoff(
    const short* __restrict__ cb, const short* __restrict__ Wa,
    const float* __restrict__ aob, const float* __restrict__ ln1g,
    const float* __restrict__ ln1b, const short* __restrict__ Wi,
    const short* __restrict__ Wf, const float* __restrict__ ib,
    const float* __restrict__ fb, const float* __restrict__ ln2g,
    const float* __restrict__ ln2b, short* xb,
    const short* __restrict__ Wqkv2, const float* __restrict__ qb2,
    const float* __restrict__ kb2, const float* __restrict__ vb2,
    short* qkvout) {
  __shared__ short SM[37888];  // 75776 B -> still 2 blocks/CU
  int tid = threadIdx.x, lane = tid & 63, wave = tid >> 6;
  int row16 = lane & 15, quad = lane >> 4;
  int tok0 = blockIdx.x * 128 + wave * 16;
  short* mySt = SM + 16384 + wave * 576;   // 16 x 36 stash (FF1->FF2)
  short* myX  = SM + 20992 + wave * 2112;  // 16 x 132 (residual -> x' -> x'')
  int xr = lane >> 2, xs = (lane & 3) * 32;  // wide 128-col row IO
  int lb = lane * 16;                        // linear fragment byte offset

  // ---- prologue: Wa (32KB linear) -> bufs; residual -> myX
  {
    #pragma unroll
    for (int t = 0; t < 4; ++t)
      async16((char*)SM + t * 8192 + wave * 1024,
              (const char*)Wa + t * 8192 + wave * 1024 + lb);
    const short* src = xb + (size_t)(tok0 + xr) * HID_ + xs;
    bf8s x0 = *(const bf8s*)(src);
    bf8s x1 = *(const bf8s*)(src + 8);
    bf8s x2 = *(const bf8s*)(src + 16);
    bf8s x3 = *(const bf8s*)(src + 24);
    short* dst = myX + xr * 132 + xs;
    *(bf8s*)(dst) = x0;      *(bf8s*)(dst + 8) = x1;
    *(bf8s*)(dst + 16) = x2; *(bf8s*)(dst + 24) = x3;
  }

  const short* arow = cb + (size_t)(tok0 + row16) * 128 + quad * 8;
  bf8s av[4];
  #pragma unroll
  for (int ki = 0; ki < 4; ++ki) av[ki] = *(const bf8s*)(arow + ki * 32);
  __syncthreads();  // B1: Wa landed

  // ---- phase A: AO linear, conflict-free fragment reads ----
  f32x4 acc[8] = {};
  #pragma unroll
  for (int ki = 0; ki < 4; ++ki)
    #pragma unroll
    for (int ot = 0; ot < 8; ++ot) {
      bf8s b = ldsb(SM, ot * 4096 + ki * 1024 + lb);
      acc[ot] = MFMA16(av[ki], b, acc[ot]);
    }
  __syncthreads();  // B2: all waves done reading Wa -> bufs reusable

  // issue FF chunk 0 (Wi rows 0..31 -> side0-lo, Wf k 0..31 -> side0-hi)
  {
    async16((char*)SM + wave * 1024, (const char*)Wi + wave * 1024 + lb);
    async16((char*)SM + 16384 + wave * 1024,
            (const char*)Wf + wave * 16384 + lb);
  }

  // AO epilogue: bias + residual(myX) + LN1 -> x'
  {
    float sum[4] = {}, ssq[4] = {};
    #pragma unroll
    for (int ot = 0; ot < 8; ++ot) {
      int col = ot * 16 + row16;
      float bi = aob[col];
      #pragma unroll
      for (int r = 0; r < 4; ++r) {
        float v = acc[ot][r] + bi + bf2f(myX[(quad * 4 + r) * 132 + col]);
        acc[ot][r] = v;
        sum[r] += v; ssq[r] += v * v;
      }
    }
    #pragma unroll
    for (int m = 1; m <= 8; m <<= 1)
      #pragma unroll
      for (int r = 0; r < 4; ++r) {
        sum[r] += __shfl_xor(sum[r], m);
        ssq[r] += __shfl_xor(ssq[r], m);
      }
    float mean[4], rstd[4];
    #pragma unroll
    for (int r = 0; r < 4; ++r) {
      mean[r] = sum[r] / 128.f;
      float var = ssq[r] / 128.f - mean[r] * mean[r];
      rstd[r] = rsqrtf(var + 1e-5f);
    }
    #pragma unroll
    for (int ot = 0; ot < 8; ++ot) {
      int col = ot * 16 + row16;
      float gg = ln1g[col], bb2 = ln1b[col];
      #pragma unroll
      for (int r = 0; r < 4; ++r)
        acc[ot][r] = (acc[ot][r] - mean[r]) * rstd[r] * gg + bb2;  // x'
    }
  }

  // transpose x' -> myX (residual consumed); reload av frags. x' STAYS here.
  #pragma unroll
  for (int ot = 0; ot < 8; ++ot) {
    int col = ot * 16 + row16;
    #pragma unroll
    for (int r = 0; r < 4; ++r)
      myX[(quad * 4 + r) * 132 + col] = f2bf(acc[ot][r]);
  }
  #pragma unroll
  for (int ki = 0; ki < 4; ++ki)
    av[ki] = *(const bf8s*)(myX + row16 * 132 + ki * 32 + quad * 8);
  __syncthreads();  // B3: chunk 0 landed

  // ---- phase B: FF, 16 chunks of 32 inters, dbuf'd DMA prefetch ----
  f32x4 acc2[8] = {};
  for (int c = 0; c < 16; ++c) {
    int side = c & 1;
    if (c < 15) {  // prefetch chunk c+1 into the other side
      int cn = c + 1, sn = cn & 1;
      async16((char*)SM + sn * 8192 + wave * 1024,
              (const char*)Wi + cn * 8192 + wave * 1024 + lb);
      async16((char*)SM + 16384 + sn * 8192 + wave * 1024,
              (const char*)Wf + wave * 16384 + cn * 1024 + lb);
    } else if (DOQKV) {  // prefetch QKV chunk 0 into side 0
      async16((char*)SM + wave * 1024, (const char*)Wqkv2 + wave * 1024 + lb);
      async16((char*)SM + 16384 + wave * 1024,
              (const char*)Wqkv2 + 8192 + wave * 1024 + lb);
    }

    // FF1: 2 out-tiles (rows c*32..+31 = fragment tiles 2c,2c+1), linear reads
    #pragma unroll
    for (int ot = 0; ot < 2; ++ot) {
      f32x4 hacc = {};
      #pragma unroll
      for (int ki = 0; ki < 4; ++ki) {
        bf8s b = ldsb(SM, side * 8192 + ot * 4096 + ki * 1024 + lb);
        hacc = MFMA16(av[ki], b, hacc);
      }
      float bi = ib[c * 32 + ot * 16 + row16];
      #pragma unroll
      for (int r = 0; r < 4; ++r)
        mySt[(quad * 4 + r) * 36 + ot * 16 + row16] =
            f2bf(fmaxf(hacc[r] + bi, 0.f));
    }
    // FF2: h (16x32) x Wf k-slice c -> acc2, linear reads
    bf8s ha = *(const bf8s*)(mySt + row16 * 36 + quad * 8);
    #pragma unroll
    for (int ot = 0; ot < 8; ++ot) {
      bf8s bB = ldsb(SM, 16384 + side * 8192 + ot * 1024 + lb);
      acc2[ot] = MFMA16(ha, bB, acc2[ot]);
    }
    __syncthreads();  // drain prefetch; protect buffer rotation
  }

  // FF epilogue: + fb + x'(myX) + LN2 -> x''
  {
    float sum[4] = {}, ssq[4] = {};
    #pragma unroll
    for (int ot = 0; ot < 8; ++ot) {
      int col = ot * 16 + row16;
      float bi = fb[col];
      #pragma unroll
      for (int r = 0; r < 4; ++r) {
        float v = acc2[ot][r] + bi + bf2f(myX[(quad * 4 + r) * 132 + col]);
        acc2[ot][r] = v;
        sum[r] += v; ssq[r] += v * v;
      }
    }
    #pragma unroll
    for (int m = 1; m <= 8; m <<= 1)
      #pragma unroll
      for (int r = 0; r < 4; ++r) {
        sum[r] += __shfl_xor(sum[r], m);
        ssq[r] += __shfl_xor(ssq[r], m);
      }
    float mean[4], rstd[4];
    #pragma unroll
    for (int r = 0; r < 4; ++r) {
      mean[r] = sum[r] / 128.f;
      float var = ssq[r] / 128.f - mean[r] * mean[r];
      rstd[r] = rsqrtf(var + 1e-5f);
    }
    #pragma unroll
    for (int ot = 0; ot < 8; ++ot) {
      int col = ot * 16 + row16;
      float gg = ln2g[col], bb2 = ln2b[col];
      #pragma unroll
      for (int r = 0; r < 4; ++r)
        acc2[ot][r] = (acc2[ot][r] - mean[r]) * rstd[r] * gg + bb2;
    }
  }

  // transpose x'' -> myX (x' dead); wide coalesced xb store
  #pragma unroll
  for (int ot = 0; ot < 8; ++ot) {
    int col = ot * 16 + row16;
    #pragma unroll
    for (int r = 0; r < 4; ++r)
      myX[(quad * 4 + r) * 132 + col] = f2bf(acc2[ot][r]);
  }
  {
    const short* src = myX + xr * 132 + xs;
    short* dst = xb + (size_t)(tok0 + xr) * HID_ + xs;
    #pragma unroll
    for (int j = 0; j < 4; ++j)
      *(bf8s*)(dst + j * 8) = *(const bf8s*)(src + j * 8);
  }

  if (DOQKV) {
    // ---- tail: next-layer QKV, 6 chunks of 4 fragment tiles (16KB), dbuf'd
    bf8s av2[4];
    #pragma unroll
    for (int ki = 0; ki < 4; ++ki)
      av2[ki] = *(const bf8s*)(myX + row16 * 132 + ki * 32 + quad * 8);
    for (int j = 0; j < 6; ++j) {
      int side = j & 1;
      if (j < 5) {
        int jn = j + 1, sn = jn & 1;
        async16((char*)SM + sn * 8192 + wave * 1024,
                (const char*)Wqkv2 + jn * 16384 + wave * 1024 + lb);
        async16((char*)SM + 16384 + sn * 8192 + wave * 1024,
                (const char*)Wqkv2 + jn * 16384 + 8192 + wave * 1024 + lb);
      }
      f32x4 acc3[4] = {};
      #pragma unroll
      for (int ki = 0; ki < 4; ++ki)
        #pragma unroll
        for (int ot = 0; ot < 4; ++ot) {
          int bb_ = (ot < 2) ? side * 8192 + ot * 4096
                             : 16384 + side * 8192 + (ot - 2) * 4096;
          bf8s b = ldsb(SM, bb_ + ki * 1024 + lb);
          acc3[ot] = MFMA16(av2[ki], b, acc3[ot]);
        }
      const float* bp = (j < 2) ? qb2 : ((j < 4) ? kb2 : vb2);
      float osc = (j < 2) ? 0.125f : 1.0f;
      #pragma unroll
      for (int ot = 0; ot < 4; ++ot) {
        int col = ot * 16 + row16;
        float bi = bp[(j & 1) * 64 + col];
        #pragma unroll
        for (int r = 0; r < 4; ++r)
          myX[(quad * 4 + r) * 132 + col] = f2bf((acc3[ot][r] + bi) * osc);
      }
      {
        int xr2 = lane >> 2, xs2 = (lane & 3) * 16;
        const short* src = myX + xr2 * 132 + xs2;
        short* dst = qkvout + (size_t)(tok0 + xr2) * 384 + j * 64 + xs2;
        *(bf8s*)(dst) = *(const bf8s*)(src);
        *(bf8s*)(dst + 8) = *(const bf8s*)(src + 8);
      }
      __syncthreads();  // drain j+1 DMA; protect buffer rotation
    }
  }
}

// ---------------- flash attention ----------------
// Round-23: (a) K/V LDS double-buffered -> ONE barrier per k-tile (was 2).
// Skew proof: a wave writing buf[t&1] can only coexist with waves computing
// tile t-1 from buf[(t-1)&1] (all passed barrier t-1; none can pass barrier t
// until every wave wrote buf[t&1]). (b) Pl stride 72->68 (34 words ≡ 2 mod 8:
// quad offsets {0,8,16,24}) -- P-stash scalar writes were 4-way conflicted.
__global__ __launch_bounds__(512) void k_attn(const short* __restrict__ qkv,
                                              short* __restrict__ O) {
  __shared__ short Kl[2][64 * 72];   // 64 keys x 64 d, stride 72, dbuf
  __shared__ short Vtl[2][64 * 72];  // 64 d x 64 keys, stride 72, dbuf
  __shared__ short Pl[8][16 * 68];   // per-wave P stash (16 q x 64 k), stride 68

  int tid = threadIdx.x, lane = tid & 63, wave = tid >> 6;
  int row16 = lane & 15, quad = lane >> 4;
  int b = blockIdx.x >> 2, h = (blockIdx.x >> 1) & 1, qhalf = blockIdx.x & 1;
  const short* base  = qkv + (size_t)b * S_ * 384;
  const short* kbase = base + 128 + h * 64;
  const short* vbase = base + 256 + h * 64;
  int q0 = qhalf * 256 + wave * 32;

  bf8s qa[2][2];
  #pragma unroll
  for (int qf = 0; qf < 2; ++qf) {
    const short* qrow = base + h * 64 +
        (size_t)(q0 + qf * 16 + row16) * 384 + quad * 8;
    qa[qf][0] = *(const bf8s*)(qrow);
    qa[qf][1] = *(const bf8s*)(qrow + 32);
  }

  int krow = tid >> 3, dgk = tid & 7;
  int vkey = tid & 63, dgv = tid >> 6;
  const short* kptr = kbase + (size_t)krow * 384 + dgk * 8;
  const short* vptr = vbase + (size_t)vkey * 384 + dgv * 8;
  bf8s kst = *(const bf8s*)(kptr);
  bf8s vst = *(const bf8s*)(vptr);

  float li[2][4] = {};
  f32x4 oacc[2][4] = {};
  short* myP = &Pl[wave][0];

  for (int kt0 = 0; kt0 < S_; kt0 += 64) {
    int bs = (kt0 >> 6) & 1;
    *(bf8s*)(&Kl[bs][krow * 72 + dgk * 8]) = kst;
    #pragma unroll
    for (int j = 0; j < 8; ++j) Vtl[bs][(dgv * 8 + j) * 72 + vkey] = vst[j];
    __syncthreads();  // buf[bs] complete; prev tile used buf[bs^1]
    if (kt0 + 64 < S_) {
      kst = *(const bf8s*)(kptr + (size_t)(kt0 + 64) * 384);
      vst = *(const bf8s*)(vptr + (size_t)(kt0 + 64) * 384);
    }

    f32x4 sc[2][4] = {};
    #pragma unroll
    for (int ks = 0; ks < 4; ++ks) {
      const short* kp = &Kl[bs][(ks * 16 + row16) * 72 + quad * 8];
      bf8s k0 = *(const bf8s*)(kp);
      bf8s k1 = *(const bf8s*)(kp + 32);
      sc[0][ks] = MFMA16(qa[0][0], k0, sc[0][ks]);
      sc[0][ks] = MFMA16(qa[0][1], k1, sc[0][ks]);
      sc[1][ks] = MFMA16(qa[1][0], k0, sc[1][ks]);
      sc[1][ks] = MFMA16(qa[1][1], k1, sc[1][ks]);
    }

    #pragma unroll
    for (int qf = 0; qf < 2; ++qf) {
      #pragma unroll
      for (int ks = 0; ks < 4; ++ks)
        #pragma unroll
        for (int r = 0; r < 4; ++r) {
          float pv = __expf(sc[qf][ks][r]);
          li[qf][r] += pv;
          myP[(quad * 4 + r) * 68 + ks * 16 + row16] = f2bf(pv);
        }
      bf8s pa0 = *(const bf8s*)(&myP[row16 * 68 + quad * 8]);
      bf8s pa1 = *(const bf8s*)(&myP[row16 * 68 + 32 + quad * 8]);
      #pragma unroll
      for (int dt = 0; dt < 4; ++dt) {
        const short* vp = &Vtl[bs][(dt * 16 + row16) * 72 + quad * 8];
        bf8s v0 = *(const bf8s*)(vp);
        bf8s v1 = *(const bf8s*)(vp + 32);
        oacc[qf][dt] = MFMA16(pa0, v0, oacc[qf][dt]);
        oacc[qf][dt] = MFMA16(pa1, v1, oacc[qf][dt]);
      }
    }
  }

  #pragma unroll
  for (int qf = 0; qf < 2; ++qf) {
    float inv[4];
    #pragma unroll
    for (int r = 0; r < 4; ++r) {
      float t = li[qf][r];
      #pragma unroll
      for (int m = 1; m <= 8; m <<= 1) t += __shfl_xor(t, m);
      inv[r] = 1.f / t;
    }
    size_t trow = (size_t)(b * S_ + q0 + qf * 16 + quad * 4);
    #pragma unroll
    for (int dt = 0; dt < 4; ++dt)
      #pragma unroll
      for (int r = 0; r < 4; ++r)
        O[(trow + r) * HID_ + h * 64 + dt * 16 + row16] =
            f2bf(oacc[qf][dt][r] * inv[r]);
  }
}

// ---------------- classifier ----------------
// 128 blocks (one per batch) x 64 lanes: 2 cols/lane, shuffle-tree reduce.
__global__ __launch_bounds__(64) void k_clf(const short* __restrict__ xb,
    const short* __restrict__ Wc, const float* __restrict__ cbias, float* out) {
  int b = blockIdx.x, lane = threadIdx.x;
  const short* xr = xb + (size_t)b * S_ * HID_;
  float x0 = bf2f(xr[lane * 2]), x1 = bf2f(xr[lane * 2 + 1]);
  #pragma unroll
  for (int c = 0; c < 2; ++c) {
    float s = x0 * bf2f(Wc[c * HID_ + lane * 2]) +
              x1 * bf2f(Wc[c * HID_ + lane * 2 + 1]);
    #pragma unroll
    for (int m = 32; m >= 1; m >>= 1) s += __shfl_xor(s, m);
    if (lane == 0) out[b * 2 + c] = s + cbias[c];
  }
}

// ---------------- launcher ----------------
extern "C" void kernel_launch(void* const* d_in, const int* in_sizes, int n_in,
                              void* d_out, int out_size, void* d_ws, size_t ws_size,
                              hipStream_t stream) {
  const int*   ids     = (const int*)d_in[0];
  const float* tok_emb = (const float*)d_in[1];
  const float* pos_emb = (const float*)d_in[2];
  const float* ln_g    = (const float*)d_in[3];
  const float* ln_bb   = (const float*)d_in[4];
  const float* qw      = (const float*)d_in[5];
  const float* qbias   = (const float*)d_in[6];
  const float* kw      = (const float*)d_in[7];
  const float* kbias   = (const float*)d_in[8];
  const float* vw      = (const float*)d_in[9];
  const float* vbias   = (const float*)d_in[10];
  const float* aow     = (const float*)d_in[11];
  const float* aobias  = (const float*)d_in[12];
  const float* iw      = (const float*)d_in[13];
  const float* ibias   = (const float*)d_in[14];
  const float* fow     = (const float*)d_in[15];
  const float* fbias   = (const float*)d_in[16];
  const float* ln1g    = (const float*)d_in[17];
  const float* ln1b    = (const float*)d_in[18];
  const float* ln2g    = (const float*)d_in[19];
  const float* ln2b    = (const float*)d_in[20];
  const float* clfw    = (const float*)d_in[21];
  const float* clfb    = (const float*)d_in[22];

  char* ws = (char*)d_ws;
  short* WQ  = (short*)ws;                                   // 787 KB quantized weights
  short* xb  = (short*)(ws + 1048576);                       // bf16 trunk (16.8 MB)
  short* qkv = (short*)(ws + 1048576 + 16777216);            // [tok][384] (50.3 MB)
  short* cb_ = qkv + (size_t)M_ * 384;                       // ctx [tok][128] (16.8 MB)

  k_qe<<<13 + M_ / 32, 1024, 0, stream>>>(qw, kw, vw, aow, iw, fow, clfw, WQ,
                                          ids, tok_emb, pos_emb, ln_g, ln_bb, xb);

  const short* Wqkv0 = WQ;
  const short* Wqkv1 = WQ + 49152;
  const short* Wa0   = WQ + 98304;
  const short* Wa1   = WQ + 98304 + 16384;
  const short* Wi0   = WQ + 131072;
  const short* Wi1   = WQ + 131072 + 65536;
  const short* Wf0   = WQ + 262144;
  const short* Wf1   = WQ + 262144 + 65536;

  // layer 0 (k_aoff tail computes layer-1 QKV)
  k_qkv<<<dim3(M_ / 64, 3), 256, 0, stream>>>(
      xb, Wqkv0, qbias, kbias, vbias, qkv);
  k_attn<<<512, 512, 0, stream>>>(qkv, cb_);
  k_aoff<1><<<M_ / 128, 512, 0, stream>>>(
      cb_, Wa0, aobias, ln1g, ln1b, Wi0, Wf0, ibias, fbias, ln2g, ln2b, xb,
      Wqkv1, qbias + HID_, kbias + HID_, vbias + HID_, qkv);
  // layer 1
  k_attn<<<512, 512, 0, stream>>>(qkv, cb_);
  k_aoff<0><<<M_ / 128, 512, 0, stream>>>(
      cb_, Wa1, aobias + HID_, ln1g + HID_, ln1b + HID_, Wi1, Wf1,
      ibias + 512, fbias + HID_, ln2g + HID_, ln2b + HID_, xb,
      nullptr, nullptr, nullptr, nullptr, nullptr);

  k_clf<<<128, 64, 0, stream>>>(xb, WQ + 393216, clfb, (float*)d_out);
}

// Round 10
// 291.321 us; speedup vs baseline: 1.1757x; 1.1757x over previous
//
#include <hip/hip_runtime.h>

// ---------------- types / helpers ----------------
typedef short bf8s __attribute__((ext_vector_type(8)));   // 8 bf16 (4 VGPRs)
typedef float f32x4 __attribute__((ext_vector_type(4)));

#define MFMA16(a, b, c) __builtin_amdgcn_mfma_f32_16x16x32_bf16(a, b, c, 0, 0, 0)

constexpr int S_ = 512, HID_ = 128, B_ = 128, M_ = B_ * S_;

// HARD RULE (round-9 lesson): LDS row strides for any b128-accessed buffer must
// be multiples of 16B. Non-multiple strides (132/36/68 shorts) silently split
// b128 ops on odd rows -> +20% LDS-pipe time, worse than the 4-quad scalar
// conflicts they fix (which are structural: 4w ≡ 0 mod 32 for any 16B-aligned
// stride w).

__device__ inline short f2bf(float f) {  // fp32 -> bf16 (RNE)
  unsigned u = __float_as_uint(f);
  u = (u + 0x7fffu + ((u >> 16) & 1u)) >> 16;
  return (short)u;
}
__device__ inline float bf2f(short s) {
  return __uint_as_float(((unsigned)(unsigned short)s) << 16);
}

// async global->LDS, 16B/lane. LDS dst must be the WAVE-UNIFORM base (hardware
// appends lane*16); global src is per-lane. Tracked by vmcnt; the compiler's
// vmcnt(0) drain before s_barrier guarantees completion.
__device__ __forceinline__ void async16(void* lds, const void* g) {
  __builtin_amdgcn_global_load_lds(
      (const __attribute__((address_space(1))) unsigned int*)g,
      (__attribute__((address_space(3))) unsigned int*)lds, 16, 0, 0);
}

__device__ __forceinline__ bf8s ldsb(const short* base, int byteoff) {
  return *(const bf8s*)((const char*)base + byteoff);
}

__device__ inline float block_red1024(float v, float* red) {
  #pragma unroll
  for (int m = 32; m >= 1; m >>= 1) v += __shfl_xor(v, m);
  __syncthreads();
  if ((threadIdx.x & 63) == 0) red[threadIdx.x >> 6] = v;
  __syncthreads();
  float t = 0.f;
  #pragma unroll
  for (int i = 0; i < 16; ++i) t += red[i];
  return t;
}

// ---------------- FRAGMENT-MAJOR weight layout ----------------
// element (r,c) of an R x C matrix lives at
//   fi = (r>>4)*(16*C) + (c>>5)*512 + ((c>>3)&3)*128 + (r&15)*8 + (c&7)
// 16x32 fragment block (tile=r>>4, ki=c>>5) = 1KB; lane l's bf8s at l*16 bytes:
// ds_read_b128 wave-linear (0 conflicts), DMA source linear.
__device__ inline void mat_info(int mat, const float* qw, const float* kw,
                                const float* vw, const float* aow, const float* iw,
                                const float* fw, const float* cw,
                                const float** src, int* n, int* doff, int* lc) {
  if (mat < 6) {
    int l = mat / 3, which = mat % 3;
    const float* t[3] = {qw, kw, vw};
    *src = t[which] + l * 16384; *n = 16384; *doff = l * 49152 + which * 16384;
    *lc = 7;
  } else if (mat < 8) {
    int l = mat - 6;
    *src = aow + l * 16384; *n = 16384; *doff = 98304 + l * 16384; *lc = 7;
  } else if (mat < 10) {
    *src = iw + (mat - 8) * 65536; *n = 65536; *doff = 131072 + (mat - 8) * 65536;
    *lc = 7;   // Wi: 512 rows x 128 cols
  } else if (mat < 12) {
    *src = fw + (mat - 10) * 65536; *n = 65536; *doff = 262144 + (mat - 10) * 65536;
    *lc = 9;   // Wf: 128 rows x 512 cols
  } else {
    *src = cw; *n = 256; *doff = 393216; *lc = 0;
  }
}

// ---------------- fused quant (blocks 0..12) + embed (blocks 13..) ----------------
// Round-22 version (8-deep load batching, exact order) -- unchanged.
__global__ __launch_bounds__(1024) void k_qe(const float* qw, const float* kw,
    const float* vw, const float* aow, const float* iw, const float* fw,
    const float* cw, short* WQ,
    const int* __restrict__ ids, const float* __restrict__ tok,
    const float* __restrict__ pos, const float* __restrict__ g,
    const float* __restrict__ bb, short* xb) {
  __shared__ float red[16];
  int tid = threadIdx.x;
  if (blockIdx.x < 13) {  // ---- ternary quantization ----
    const float* src; int n, doff, lc;
    mat_info(blockIdx.x, qw, kw, vw, aow, iw, fw, cw, &src, &n, &doff, &lc);
    float s = 0.f;
    if (n >= 8192) {  // n is a multiple of 8192 for all big mats
      for (int i0 = tid; i0 < n; i0 += 8192) {
        float v[8];
        #pragma unroll
        for (int j = 0; j < 8; ++j) v[j] = src[i0 + j * 1024];  // 8 in flight
        #pragma unroll
        for (int j = 0; j < 8; ++j) s += fabsf(v[j]);           // exact order
      }
    } else {
      for (int i = tid; i < n; i += 1024) s += fabsf(src[i]);
    }
    s = block_red1024(s, red);
    float delta = 0.7f * s / (float)n;
    float s2 = 0.f, c2 = 0.f;
    if (n >= 8192) {
      for (int i0 = tid; i0 < n; i0 += 8192) {
        float v[8];
        #pragma unroll
        for (int j = 0; j < 8; ++j) v[j] = src[i0 + j * 1024];
        #pragma unroll
        for (int j = 0; j < 8; ++j) {
          float a = fabsf(v[j]);
          s2 += (a > delta) ? a : 0.f;   // +0.0f: exact identity
          c2 += (a > delta) ? 1.f : 0.f;
        }
      }
    } else {
      for (int i = tid; i < n; i += 1024) {
        float a = fabsf(src[i]);
        if (a > delta) { s2 += a; c2 += 1.f; }
      }
    }
    s2 = block_red1024(s2, red);
    c2 = block_red1024(c2, red);
    float alpha = s2 / fmaxf(c2, 1.f);
    if (lc) {  // output-major fragment write: vector reads + 16B stores
      int nf8 = n >> 3;
      for (int fo8 = tid; fo8 < nf8; fo8 += 1024) {
        int fo = fo8 << 3;
        int tile = fo >> (lc + 4);
        int rem = fo & ((16 << lc) - 1);
        int kblk = rem >> 9;
        int rem2 = rem & 511;
        int sub = rem2 >> 7;
        int r16 = (rem2 >> 3) & 15;
        int r = (tile << 4) | r16;
        int cbase = (kblk << 5) | (sub << 3);
        const float* sp = src + ((size_t)r << lc) + cbase;
        float4 w0 = *(const float4*)(sp);
        float4 w1 = *(const float4*)(sp + 4);
        float wv[8] = {w0.x, w0.y, w0.z, w0.w, w1.x, w1.y, w1.z, w1.w};
        bf8s q;
        #pragma unroll
        for (int j = 0; j < 8; ++j) {
          float w = wv[j];
          q[j] = (fabsf(w) > delta) ? f2bf(w > 0.f ? alpha : -alpha) : (short)0;
        }
        *(bf8s*)(WQ + doff + fo) = q;
      }
    } else {  // clf: row-major scalar
      for (int i = tid; i < n; i += 1024) {
        float w = src[i];
        WQ[doff + i] = (fabsf(w) > delta) ? f2bf(w > 0.f ? alpha : -alpha) : (short)0;
      }
    }
  } else {  // ---- embedding + LN: 2 tokens/wave, float4/lane ----
    int wave = tid >> 6, lane = tid & 63;
    int half = lane >> 5, l32 = lane & 31;
    int t = (blockIdx.x - 13) * 32 + wave * 2 + half;
    int s = t & (S_ - 1);
    int id = ids[t];
    int d0 = l32 * 4;
    float4 te = *(const float4*)(tok + (size_t)id * HID_ + d0);
    float4 pe = *(const float4*)(pos + (size_t)s * HID_ + d0);
    float e0 = te.x + pe.x, e1 = te.y + pe.y, e2 = te.z + pe.z, e3 = te.w + pe.w;
    float sum = e0 + e1 + e2 + e3;
    float ssq = e0 * e0 + e1 * e1 + e2 * e2 + e3 * e3;
    #pragma unroll
    for (int m = 16; m >= 1; m >>= 1) {  // stays within 32-lane half
      sum += __shfl_xor(sum, m);
      ssq += __shfl_xor(ssq, m);
    }
    float mean = sum / 128.f;
    float var = ssq / 128.f - mean * mean;
    float rs = rsqrtf(var + 1e-5f);
    float4 g4 = *(const float4*)(g + d0);
    float4 b4 = *(const float4*)(bb + d0);
    short4 o;
    o.x = f2bf((e0 - mean) * rs * g4.x + b4.x);
    o.y = f2bf((e1 - mean) * rs * g4.y + b4.y);
    o.z = f2bf((e2 - mean) * rs * g4.z + b4.z);
    o.w = f2bf((e3 - mean) * rs * g4.w + b4.w);
    *(short4*)(xb + (size_t)t * HID_ + d0) = o;
  }
}

// ---------------- QKV linear (layer 0): SINGLE-PASS q+k+v ----------------
// Round-24: 3 launches merged into 1. Each block computes q,k,v for its 64
// tokens sequentially: av registers reused 3x (A-reads /3), 6 chunks of 16KB
// (64 out-cols) double-buffered with the proven k_aoff-tail DMA pattern.
// scr stride 136 shorts = 272B (16B multiple -- round-9 rule). LDS: bufs 32KB
// + scr 4x16x136x2B = 50176B -> 3 blocks/CU.
__global__ __launch_bounds__(256) void k_qkv(
    const short* __restrict__ A, const short* __restrict__ W,
    const float* __restrict__ b0, const float* __restrict__ b1,
    const float* __restrict__ b2, short* outb) {
  __shared__ short SM[25088];  // 32KB bufs + 17408B scr
  int tid = threadIdx.x, lane = tid & 63, wave = tid >> 6;
  int row16 = lane & 15, quad = lane >> 4;
  int tok0 = blockIdx.x * 64 + wave * 16;
  short* scr = SM + 16384 + wave * 2176;  // 16 x 136
  int lb = lane * 16;

  // issue chunk 0 (16KB) -> side 0: 4 DMA calls/wave
  #pragma unroll
  for (int t = 0; t < 4; ++t)
    async16((char*)SM + (wave * 4 + t) * 1024,
            (const char*)W + (wave * 4 + t) * 1024 + lb);

  const short* arow = A + (size_t)(tok0 + row16) * 128 + quad * 8;
  bf8s av[4];
  #pragma unroll
  for (int ki = 0; ki < 4; ++ki) av[ki] = *(const bf8s*)(arow + ki * 32);
  __syncthreads();  // chunk 0 landed

  for (int j = 0; j < 6; ++j) {
    int side = j & 1;
    if (j < 5) {  // prefetch chunk j+1 into the other side
      int jn = j + 1, sn = jn & 1;
      #pragma unroll
      for (int t = 0; t < 4; ++t)
        async16((char*)SM + sn * 16384 + (wave * 4 + t) * 1024,
                (const char*)W + jn * 16384 + (wave * 4 + t) * 1024 + lb);
    }
    // 4 col-tiles x 4 ki = 16 MFMAs from side buffer (conflict-free linear)
    f32x4 acc[4] = {};
    #pragma unroll
    for (int ki = 0; ki < 4; ++ki)
      #pragma unroll
      for (int ot = 0; ot < 4; ++ot) {
        bf8s b = ldsb(SM, side * 16384 + ot * 4096 + ki * 1024 + lb);
        acc[ot] = MFMA16(av[ki], b, acc[ot]);
      }
    // epilogue: bias + scale, transpose through scr, wide store
    int mtx = j >> 1;
    const float* bp = (mtx == 0) ? b0 : ((mtx == 1) ? b1 : b2);
    float osc = (mtx == 0) ? 0.125f : 1.0f;  // fold 1/sqrt(64) into Q
    #pragma unroll
    for (int ot = 0; ot < 4; ++ot) {
      int col = ot * 16 + row16;
      float bi = bp[(j & 1) * 64 + col];
      #pragma unroll
      for (int r = 0; r < 4; ++r)
        scr[(quad * 4 + r) * 136 + col] = f2bf((acc[ot][r] + bi) * osc);
    }
    {
      int xr2 = lane >> 2, xs2 = (lane & 3) * 16;
      const short* src = scr + xr2 * 136 + xs2;
      short* dst = outb + (size_t)(tok0 + xr2) * 384 + mtx * 128 +
                   (j & 1) * 64 + xs2;
      *(bf8s*)(dst) = *(const bf8s*)(src);
      *(bf8s*)(dst + 8) = *(const bf8s*)(src + 8);
    }
    __syncthreads();  // drain j+1 DMA; protect buffer rotation + scr reuse
  }
}

// ---------------- fused AO+LN1+FF1+FF2+LN2 [+ next-layer QKV] ----------------
// Round-8 version RESTORED byte-exact (myX 144 / stash 40 -- all strides 16B
// multiples; the 2.69M scalar-column conflicts are structural and cheaper than
// any alignment-breaking fix).
template <int DOQKV>
__global__ __launch_bounds__(512, 4) void k_aoff(
    const short* __restrict__ cb, const short* __restrict__ Wa,
    const float* __restrict__ aob, const float* __restrict__ ln1g,
    const float* __restrict__ ln1b, const short* __restrict__ Wi,
    const short* __restrict__ Wf, const float* __restrict__ ib,
    const float* __restrict__ fb, const float* __restrict__ ln2g,
    const float* __restrict__ ln2b, short* xb,
    const short* __restrict__ Wqkv2, const float* __restrict__ qb2,
    const float* __restrict__ kb2, const float* __restrict__ vb2,
    short* qkvout) {
  __shared__ short SM[39936];  // 79872 B
  int tid = threadIdx.x, lane = tid & 63, wave = tid >> 6;
  int row16 = lane & 15, quad = lane >> 4;
  int tok0 = blockIdx.x * 128 + wave * 16;
  short* mySt = SM + 16384 + wave * 640;   // 16 x 40 stash (FF1->FF2)
  short* myX  = SM + 21504 + wave * 2304;  // 16 x 144 (residual -> x' -> x'')
  int xr = lane >> 2, xs = (lane & 3) * 32;  // wide 128-col row IO
  int lb = lane * 16;                        // linear fragment byte offset

  // ---- prologue: Wa (32KB linear) -> bufs; residual -> myX
  {
    #pragma unroll
    for (int t = 0; t < 4; ++t)
      async16((char*)SM + t * 8192 + wave * 1024,
              (const char*)Wa + t * 8192 + wave * 1024 + lb);
    const short* src = xb + (size_t)(tok0 + xr) * HID_ + xs;
    bf8s x0 = *(const bf8s*)(src);
    bf8s x1 = *(const bf8s*)(src + 8);
    bf8s x2 = *(const bf8s*)(src + 16);
    bf8s x3 = *(const bf8s*)(src + 24);
    short* dst = myX + xr * 144 + xs;
    *(bf8s*)(dst) = x0;      *(bf8s*)(dst + 8) = x1;
    *(bf8s*)(dst + 16) = x2; *(bf8s*)(dst + 24) = x3;
  }

  const short* arow = cb + (size_t)(tok0 + row16) * 128 + quad * 8;
  bf8s av[4];
  #pragma unroll
  for (int ki = 0; ki < 4; ++ki) av[ki] = *(const bf8s*)(arow + ki * 32);
  __syncthreads();  // B1: Wa landed

  // ---- phase A: AO linear, conflict-free fragment reads ----
  f32x4 acc[8] = {};
  #pragma unroll
  for (int ki = 0; ki < 4; ++ki)
    #pragma unroll
    for (int ot = 0; ot < 8; ++ot) {
      bf8s b = ldsb(SM, ot * 4096 + ki * 1024 + lb);
      acc[ot] = MFMA16(av[ki], b, acc[ot]);
    }
  __syncthreads();  // B2: all waves done reading Wa -> bufs reusable

  // issue FF chunk 0 (Wi rows 0..31 -> side0-lo, Wf k 0..31 -> side0-hi)
  {
    async16((char*)SM + wave * 1024, (const char*)Wi + wave * 1024 + lb);
    async16((char*)SM + 16384 + wave * 1024,
            (const char*)Wf + wave * 16384 + lb);
  }

  // AO epilogue: bias + residual(myX) + LN1 -> x'
  {
    float sum[4] = {}, ssq[4] = {};
    #pragma unroll
    for (int ot = 0; ot < 8; ++ot) {
      int col = ot * 16 + row16;
      float bi = aob[col];
      #pragma unroll
      for (int r = 0; r < 4; ++r) {
        float v = acc[ot][r] + bi + bf2f(myX[(quad * 4 + r) * 144 + col]);
        acc[ot][r] = v;
        sum[r] += v; ssq[r] += v * v;
      }
    }
    #pragma unroll
    for (int m = 1; m <= 8; m <<= 1)
      #pragma unroll
      for (int r = 0; r < 4; ++r) {
        sum[r] += __shfl_xor(sum[r], m);
        ssq[r] += __shfl_xor(ssq[r], m);
      }
    float mean[4], rstd[4];
    #pragma unroll
    for (int r = 0; r < 4; ++r) {
      mean[r] = sum[r] / 128.f;
      float var = ssq[r] / 128.f - mean[r] * mean[r];
      rstd[r] = rsqrtf(var + 1e-5f);
    }
    #pragma unroll
    for (int ot = 0; ot < 8; ++ot) {
      int col = ot * 16 + row16;
      float gg = ln1g[col], bb2 = ln1b[col];
      #pragma unroll
      for (int r = 0; r < 4; ++r)
        acc[ot][r] = (acc[ot][r] - mean[r]) * rstd[r] * gg + bb2;  // x'
    }
  }

  // transpose x' -> myX (residual consumed); reload av frags. x' STAYS here.
  #pragma unroll
  for (int ot = 0; ot < 8; ++ot) {
    int col = ot * 16 + row16;
    #pragma unroll
    for (int r = 0; r < 4; ++r)
      myX[(quad * 4 + r) * 144 + col] = f2bf(acc[ot][r]);
  }
  #pragma unroll
  for (int ki = 0; ki < 4; ++ki)
    av[ki] = *(const bf8s*)(myX + row16 * 144 + ki * 32 + quad * 8);
  __syncthreads();  // B3: chunk 0 landed

  // ---- phase B: FF, 16 chunks of 32 inters, dbuf'd DMA prefetch ----
  f32x4 acc2[8] = {};
  for (int c = 0; c < 16; ++c) {
    int side = c & 1;
    if (c < 15) {  // prefetch chunk c+1 into the other side
      int cn = c + 1, sn = cn & 1;
      async16((char*)SM + sn * 8192 + wave * 1024,
              (const char*)Wi + cn * 8192 + wave * 1024 + lb);
      async16((char*)SM + 16384 + sn * 8192 + wave * 1024,
              (const char*)Wf + wave * 16384 + cn * 1024 + lb);
    } else if (DOQKV) {  // prefetch QKV chunk 0 into side 0
      async16((char*)SM + wave * 1024, (const char*)Wqkv2 + wave * 1024 + lb);
      async16((char*)SM + 16384 + wave * 1024,
              (const char*)Wqkv2 + 8192 + wave * 1024 + lb);
    }

    // FF1: 2 out-tiles (rows c*32..+31 = fragment tiles 2c,2c+1), linear reads
    #pragma unroll
    for (int ot = 0; ot < 2; ++ot) {
      f32x4 hacc = {};
      #pragma unroll
      for (int ki = 0; ki < 4; ++ki) {
        bf8s b = ldsb(SM, side * 8192 + ot * 4096 + ki * 1024 + lb);
        hacc = MFMA16(av[ki], b, hacc);
      }
      float bi = ib[c * 32 + ot * 16 + row16];
      #pragma unroll
      for (int r = 0; r < 4; ++r)
        mySt[(quad * 4 + r) * 40 + ot * 16 + row16] =
            f2bf(fmaxf(hacc[r] + bi, 0.f));
    }
    // FF2: h (16x32) x Wf k-slice c -> acc2, linear reads
    bf8s ha = *(const bf8s*)(mySt + row16 * 40 + quad * 8);
    #pragma unroll
    for (int ot = 0; ot < 8; ++ot) {
      bf8s bB = ldsb(SM, 16384 + side * 8192 + ot * 1024 + lb);
      acc2[ot] = MFMA16(ha, bB, acc2[ot]);
    }
    __syncthreads();  // drain prefetch; protect buffer rotation
  }

  // FF epilogue: + fb + x'(myX) + LN2 -> x''
  {
    float sum[4] = {}, ssq[4] = {};
    #pragma unroll
    for (int ot = 0; ot < 8; ++ot) {
      int col = ot * 16 + row16;
      float bi = fb[col];
      #pragma unroll
      for (int r = 0; r < 4; ++r) {
        float v = acc2[ot][r] + bi + bf2f(myX[(quad * 4 + r) * 144 + col]);
        acc2[ot][r] = v;
        sum[r] += v; ssq[r] += v * v;
      }
    }
    #pragma unroll
    for (int m = 1; m <= 8; m <<= 1)
      #pragma unroll
      for (int r = 0; r < 4; ++r) {
        sum[r] += __shfl_xor(sum[r], m);
        ssq[r] += __shfl_xor(ssq[r], m);
      }
    float mean[4], rstd[4];
    #pragma unroll
    for (int r = 0; r < 4; ++r) {
      mean[r] = sum[r] / 128.f;
      float var = ssq[r] / 128.f - mean[r] * mean[r];
      rstd[r] = rsqrtf(var + 1e-5f);
    }
    #pragma unroll
    for (int ot = 0; ot < 8; ++ot) {
      int col = ot * 16 + row16;
      float gg = ln2g[col], bb2 = ln2b[col];
      #pragma unroll
      for (int r = 0; r < 4; ++r)
        acc2[ot][r] = (acc2[ot][r] - mean[r]) * rstd[r] * gg + bb2;
    }
  }

  // transpose x'' -> myX (x' dead); wide coalesced xb store
  #pragma unroll
  for (int ot = 0; ot < 8; ++ot) {
    int col = ot * 16 + row16;
    #pragma unroll
    for (int r = 0; r < 4; ++r)
      myX[(quad * 4 + r) * 144 + col] = f2bf(acc2[ot][r]);
  }
  {
    const short* src = myX + xr * 144 + xs;
    short* dst = xb + (size_t)(tok0 + xr) * HID_ + xs;
    #pragma unroll
    for (int j = 0; j < 4; ++j)
      *(bf8s*)(dst + j * 8) = *(const bf8s*)(src + j * 8);
  }

  if (DOQKV) {
    // ---- tail: next-layer QKV, 6 chunks of 4 fragment tiles (16KB), dbuf'd
    bf8s av2[4];
    #pragma unroll
    for (int ki = 0; ki < 4; ++ki)
      av2[ki] = *(const bf8s*)(myX + row16 * 144 + ki * 32 + quad * 8);
    for (int j = 0; j < 6; ++j) {
      int side = j & 1;
      if (j < 5) {
        int jn = j + 1, sn = jn & 1;
        async16((char*)SM + sn * 8192 + wave * 1024,
                (const char*)Wqkv2 + jn * 16384 + wave * 1024 + lb);
        async16((char*)SM + 16384 + sn * 8192 + wave * 1024,
                (const char*)Wqkv2 + jn * 16384 + 8192 + wave * 1024 + lb);
      }
      f32x4 acc3[4] = {};
      #pragma unroll
      for (int ki = 0; ki < 4; ++ki)
        #pragma unroll
        for (int ot = 0; ot < 4; ++ot) {
          int bb_ = (ot < 2) ? side * 8192 + ot * 4096
                             : 16384 + side * 8192 + (ot - 2) * 4096;
          bf8s b = ldsb(SM, bb_ + ki * 1024 + lb);
          acc3[ot] = MFMA16(av2[ki], b, acc3[ot]);
        }
      const float* bp = (j < 2) ? qb2 : ((j < 4) ? kb2 : vb2);
      float osc = (j < 2) ? 0.125f : 1.0f;
      #pragma unroll
      for (int ot = 0; ot < 4; ++ot) {
        int col = ot * 16 + row16;
        float bi = bp[(j & 1) * 64 + col];
        #pragma unroll
        for (int r = 0; r < 4; ++r)
          myX[(quad * 4 + r) * 144 + col] = f2bf((acc3[ot][r] + bi) * osc);
      }
      {
        int xr2 = lane >> 2, xs2 = (lane & 3) * 16;
        const short* src = myX + xr2 * 144 + xs2;
        short* dst = qkvout + (size_t)(tok0 + xr2) * 384 + j * 64 + xs2;
        *(bf8s*)(dst) = *(const bf8s*)(src);
        *(bf8s*)(dst + 8) = *(const bf8s*)(src + 8);
      }
      __syncthreads();  // drain j+1 DMA; protect buffer rotation
    }
  }
}

// ---------------- flash attention (round-8 version RESTORED) ----------------
// grid = 512: blockIdx.x = (b<<2)|(h<<1)|qhalf. block = 512 (8 waves x 32 q).
// Single-buffer K/V, 2 barriers/tile, Pl stride 72 (16B multiple).
__global__ __launch_bounds__(512) void k_attn(const short* __restrict__ qkv,
                                              short* __restrict__ O) {
  __shared__ short Kl[64 * 72];     // 64 keys x 64 d, stride 72
  __shared__ short Vtl[64 * 72];    // 64 d x 64 keys, stride 72
  __shared__ short Pl[8][16 * 72];  // per-wave P stash (16 q x 64 k)

  int tid = threadIdx.x, lane = tid & 63, wave = tid >> 6;
  int row16 = lane & 15, quad = lane >> 4;
  int b = blockIdx.x >> 2, h = (blockIdx.x >> 1) & 1, qhalf = blockIdx.x & 1;
  const short* base  = qkv + (size_t)b * S_ * 384;
  const short* kbase = base + 128 + h * 64;
  const short* vbase = base + 256 + h * 64;
  int q0 = qhalf * 256 + wave * 32;

  bf8s qa[2][2];
  #pragma unroll
  for (int qf = 0; qf < 2; ++qf) {
    const short* qrow = base + h * 64 +
        (size_t)(q0 + qf * 16 + row16) * 384 + quad * 8;
    qa[qf][0] = *(const bf8s*)(qrow);
    qa[qf][1] = *(const bf8s*)(qrow + 32);
  }

  int krow = tid >> 3, dgk = tid & 7;
  int vkey = tid & 63, dgv = tid >> 6;
  const short* kptr = kbase + (size_t)krow * 384 + dgk * 8;
  const short* vptr = vbase + (size_t)vkey * 384 + dgv * 8;
  bf8s kst = *(const bf8s*)(kptr);
  bf8s vst = *(const bf8s*)(vptr);

  float li[2][4] = {};
  f32x4 oacc[2][4] = {};
  short* myP = &Pl[wave][0];

  for (int kt0 = 0; kt0 < S_; kt0 += 64) {
    if (kt0) __syncthreads();
    *(bf8s*)(&Kl[krow * 72 + dgk * 8]) = kst;
    #pragma unroll
    for (int j = 0; j < 8; ++j) Vtl[(dgv * 8 + j) * 72 + vkey] = vst[j];
    __syncthreads();
    if (kt0 + 64 < S_) {
      kst = *(const bf8s*)(kptr + (size_t)(kt0 + 64) * 384);
      vst = *(const bf8s*)(vptr + (size_t)(kt0 + 64) * 384);
    }

    f32x4 sc[2][4] = {};
    #pragma unroll
    for (int ks = 0; ks < 4; ++ks) {
      const short* kp = &Kl[(ks * 16 + row16) * 72 + quad * 8];
      bf8s k0 = *(const bf8s*)(kp);
      bf8s k1 = *(const bf8s*)(kp + 32);
      sc[0][ks] = MFMA16(qa[0][0], k0, sc[0][ks]);
      sc[0][ks] = MFMA16(qa[0][1], k1, sc[0][ks]);
      sc[1][ks] = MFMA16(qa[1][0], k0, sc[1][ks]);
      sc[1][ks] = MFMA16(qa[1][1], k1, sc[1][ks]);
    }

    #pragma unroll
    for (int qf = 0; qf < 2; ++qf) {
      #pragma unroll
      for (int ks = 0; ks < 4; ++ks)
        #pragma unroll
        for (int r = 0; r < 4; ++r) {
          float pv = __expf(sc[qf][ks][r]);
          li[qf][r] += pv;
          myP[(quad * 4 + r) * 72 + ks * 16 + row16] = f2bf(pv);
        }
      bf8s pa0 = *(const bf8s*)(&myP[row16 * 72 + quad * 8]);
      bf8s pa1 = *(const bf8s*)(&myP[row16 * 72 + 32 + quad * 8]);
      #pragma unroll
      for (int dt = 0; dt < 4; ++dt) {
        const short* vp = &Vtl[(dt * 16 + row16) * 72 + quad * 8];
        bf8s v0 = *(const bf8s*)(vp);
        bf8s v1 = *(const bf8s*)(vp + 32);
        oacc[qf][dt] = MFMA16(pa0, v0, oacc[qf][dt]);
        oacc[qf][dt] = MFMA16(pa1, v1, oacc[qf][dt]);
      }
    }
  }

  #pragma unroll
  for (int qf = 0; qf < 2; ++qf) {
    float inv[4];
    #pragma unroll
    for (int r = 0; r < 4; ++r) {
      float t = li[qf][r];
      #pragma unroll
      for (int m = 1; m <= 8; m <<= 1) t += __shfl_xor(t, m);
      inv[r] = 1.f / t;
    }
    size_t trow = (size_t)(b * S_ + q0 + qf * 16 + quad * 4);
    #pragma unroll
    for (int dt = 0; dt < 4; ++dt)
      #pragma unroll
      for (int r = 0; r < 4; ++r)
        O[(trow + r) * HID_ + h * 64 + dt * 16 + row16] =
            f2bf(oacc[qf][dt][r] * inv[r]);
  }
}

// ---------------- classifier ----------------
// 128 blocks (one per batch) x 64 lanes: 2 cols/lane, shuffle-tree reduce.
__global__ __launch_bounds__(64) void k_clf(const short* __restrict__ xb,
    const short* __restrict__ Wc, const float* __restrict__ cbias, float* out) {
  int b = blockIdx.x, lane = threadIdx.x;
  const short* xr = xb + (size_t)b * S_ * HID_;
  float x0 = bf2f(xr[lane * 2]), x1 = bf2f(xr[lane * 2 + 1]);
  #pragma unroll
  for (int c = 0; c < 2; ++c) {
    float s = x0 * bf2f(Wc[c * HID_ + lane * 2]) +
              x1 * bf2f(Wc[c * HID_ + lane * 2 + 1]);
    #pragma unroll
    for (int m = 32; m >= 1; m >>= 1) s += __shfl_xor(s, m);
    if (lane == 0) out[b * 2 + c] = s + cbias[c];
  }
}

// ---------------- launcher ----------------
extern "C" void kernel_launch(void* const* d_in, const int* in_sizes, int n_in,
                              void* d_out, int out_size, void* d_ws, size_t ws_size,
                              hipStream_t stream) {
  const int*   ids     = (const int*)d_in[0];
  const float* tok_emb = (const float*)d_in[1];
  const float* pos_emb = (const float*)d_in[2];
  const float* ln_g    = (const float*)d_in[3];
  const float* ln_bb   = (const float*)d_in[4];
  const float* qw      = (const float*)d_in[5];
  const float* qbias   = (const float*)d_in[6];
  const float* kw      = (const float*)d_in[7];
  const float* kbias   = (const float*)d_in[8];
  const float* vw      = (const float*)d_in[9];
  const float* vbias   = (const float*)d_in[10];
  const float* aow     = (const float*)d_in[11];
  const float* aobias  = (const float*)d_in[12];
  const float* iw      = (const float*)d_in[13];
  const float* ibias   = (const float*)d_in[14];
  const float* fow     = (const float*)d_in[15];
  const float* fbias   = (const float*)d_in[16];
  const float* ln1g    = (const float*)d_in[17];
  const float* ln1b    = (const float*)d_in[18];
  const float* ln2g    = (const float*)d_in[19];
  const float* ln2b    = (const float*)d_in[20];
  const float* clfw    = (const float*)d_in[21];
  const float* clfb    = (const float*)d_in[22];

  char* ws = (char*)d_ws;
  short* WQ  = (short*)ws;                                   // 787 KB quantized weights
  short* xb  = (short*)(ws + 1048576);                       // bf16 trunk (16.8 MB)
  short* qkv = (short*)(ws + 1048576 + 16777216);            // [tok][384] (50.3 MB)
  short* cb_ = qkv + (size_t)M_ * 384;                       // ctx [tok][128] (16.8 MB)

  k_qe<<<13 + M_ / 32, 1024, 0, stream>>>(qw, kw, vw, aow, iw, fow, clfw, WQ,
                                          ids, tok_emb, pos_emb, ln_g, ln_bb, xb);

  const short* Wqkv0 = WQ;
  const short* Wqkv1 = WQ + 49152;
  const short* Wa0   = WQ + 98304;
  const short* Wa1   = WQ + 98304 + 16384;
  const short* Wi0   = WQ + 131072;
  const short* Wi1   = WQ + 131072 + 65536;
  const short* Wf0   = WQ + 262144;
  const short* Wf1   = WQ + 262144 + 65536;

  // layer 0 (k_aoff tail computes layer-1 QKV)
  k_qkv<<<M_ / 64, 256, 0, stream>>>(
      xb, Wqkv0, qbias, kbias, vbias, qkv);
  k_attn<<<512, 512, 0, stream>>>(qkv, cb_);
  k_aoff<1><<<M_ / 128, 512, 0, stream>>>(
      cb_, Wa0, aobias, ln1g, ln1b, Wi0, Wf0, ibias, fbias, ln2g, ln2b, xb,
      Wqkv1, qbias + HID_, kbias + HID_, vbias + HID_, qkv);
  // layer 1
  k_attn<<<512, 512, 0, stream>>>(qkv, cb_);
  k_aoff<0><<<M_ / 128, 512, 0, stream>>>(
      cb_, Wa1, aobias + HID_, ln1g + HID_, ln1b + HID_, Wi1, Wf1,
      ibias + 512, fbias + HID_, ln2g + HID_, ln2b + HID_, xb,
      nullptr, nullptr, nullptr, nullptr, nullptr);

  k_clf<<<128, 64, 0, stream>>>(xb, WQ + 393216, clfb, (float*)d_out);
}